// Round 14
// baseline (92.077 us; speedup 1.0000x reference)
//
#include <hip/hip_runtime.h>
#include <stdint.h>

#define NN 4096
#define NB2 16         // NN / 256
#define BK 64          // K-step

// trimm grid: [0,260) units (d desc; nu(d)=ceil((d+1)/4) K-units/tile, each
// <=16 K-tiles), [260,380) strict-upper 256^2 zero tiles.
#define NUNITS 260
#define ZBASE 260
#define TGRID 380
#define NSPLIT 78      // tiles with nu>=2 (d>=4)
#define NWSLOTS 202    // units belonging to split tiles (bids 0..201)

// prep grid: [0,4096) A rows, [4096,8192) B 64x64 subtiles;
// fallback adds [8192,8504) zero-init (78 tiles x 4 stripes)
#define PGRID_W 8192
#define PGRID_A 8504

typedef __bf16 bf16x8 __attribute__((ext_vector_type(8)));
typedef float f32x4 __attribute__((ext_vector_type(4)));
typedef unsigned short ushort8 __attribute__((ext_vector_type(8)));

__device__ __forceinline__ unsigned short f2bf(float x) {
    union { float f; unsigned int u; } v; v.f = x;
    unsigned int u = v.u;
    u += 0x7fffu + ((u >> 16) & 1u);
    return (unsigned short)(u >> 16);
}

#define GLOAD16(g, l) __builtin_amdgcn_global_load_lds( \
    (const __attribute__((address_space(1))) unsigned int*)(g), \
    (__attribute__((address_space(3))) unsigned int*)(l), 16, 0, 0)

// split tile index z (0..77) -> (bi,bj,nu,u0); d descending 15..4
__device__ __forceinline__ void split_decode(int z, int& bi, int& bj, int& nu, int& u0) {
    int d = 15, acc = 0;
    for (;;) {
        nu = (d + 4) >> 2;
        int cnt = NB2 - d;
        if (z < cnt) { bj = z; bi = z + d; u0 = acc + z * nu; return; }
        z -= cnt; acc += cnt * nu; --d;
    }
}

// ---- fused prep ----
__global__ __launch_bounds__(256) void prep(const float* __restrict__ A,
                                            const float* __restrict__ B,
                                            unsigned short* __restrict__ Ab,
                                            unsigned short* __restrict__ Bt,
                                            float* __restrict__ C) {
    __shared__ float tile[64][65];
    int bid = blockIdx.x;
    int tid = threadIdx.x;

    if (bid < 4096) {
        int i = bid;
        int nslots = ((i >> 8) + 1) * 32;
        const float4* src = reinterpret_cast<const float4*>(A + (size_t)i * NN);
        unsigned short* dst = Ab + (size_t)i * NN;
        for (int p = tid; p < nslots; p += 256) {
            float4 x0 = src[p * 2], x1 = src[p * 2 + 1];
            ushort8 o;
            o[0] = f2bf(x0.x); o[1] = f2bf(x0.y); o[2] = f2bf(x0.z); o[3] = f2bf(x0.w);
            o[4] = f2bf(x1.x); o[5] = f2bf(x1.y); o[6] = f2bf(x1.z); o[7] = f2bf(x1.w);
            *reinterpret_cast<ushort8*>(dst + p * 8) = o;
        }
        return;
    }
    if (bid < 8192) {
        int s = bid - 4096;
        int n64 = s >> 6, k64 = s & 63;
        if (k64 < (n64 & ~3)) return;
        int n0 = n64 * 64, k0 = k64 * 64;
        int tx = tid & 63, ty = tid >> 6;
#pragma unroll
        for (int r = 0; r < 16; ++r) {
            int k = ty + r * 4;
            tile[k][tx] = B[(size_t)(k0 + k) * NN + n0 + tx];
        }
        __syncthreads();
#pragma unroll
        for (int r = 0; r < 16; ++r) {
            int n = ty + r * 4;
            Bt[(size_t)(n0 + n) * NN + k0 + tx] = f2bf(tile[tx][n]);
        }
        return;
    }
    // atomic-fallback zero-init for split C tiles
    {
        int z = bid - 8192;            // 0..311
        int bi, bj, nu, u0; split_decode(z >> 2, bi, bj, nu, u0);
        int part = z & 3;
        float4 zf = make_float4(0.f, 0.f, 0.f, 0.f);
        float4* cp = reinterpret_cast<float4*>(C + (size_t)(bi * 256 + part * 64) * NN + (size_t)bj * 256);
#pragma unroll
        for (int i2 = 0; i2 < 16; ++i2) {
            int slot = tid + i2 * 256;
            int row = slot >> 6, c4 = slot & 63;
            cp[(size_t)row * (NN / 4) + c4] = zf;
        }
    }
}

// ---- triangular GEMM: 256^2, 8 waves, 4-phase/K-tile, half-tile ring,
//      counted vmcnt(4) (m201-style schedule) ----
__global__ __launch_bounds__(512, 1) void trimm(const unsigned short* __restrict__ Ab,
                                                const unsigned short* __restrict__ Bt,
                                                float* __restrict__ C,
                                                float* __restrict__ W,
                                                int useW) {
    int bid = blockIdx.x;
    int tid = threadIdx.x;
    int lane = tid & 63;
    int w = tid >> 6;

    if (bid >= ZBASE) {
        // strict upper 256^2 tile: zero-fill
        int r = bid - ZBASE, bi = 0;
        while (r >= NB2 - 1 - bi) { r -= NB2 - 1 - bi; ++bi; }
        int bj = bi + 1 + r;
        float4 z = make_float4(0.f, 0.f, 0.f, 0.f);
        float4* cp = reinterpret_cast<float4*>(C + (size_t)bi * 256 * NN + (size_t)bj * 256);
#pragma unroll
        for (int i2 = 0; i2 < 32; ++i2) {
            int slot = tid + i2 * 512;
            int row = slot >> 6, c4 = slot & 63;
            cp[(size_t)row * (NN / 4) + c4] = z;
        }
        return;
    }

    // unit decode (R10-verified): d desc 15..0; nu=ceil((d+1)/4); ntk=4(d+1)
    int bi, bj, k_lo, nt;
    bool atom;
    {
        int r = bid, d = 15, nu;
        for (;;) {
            nu = (d + 4) >> 2;
            int cnt = (NB2 - d) * nu;
            if (r < cnt) break;
            r -= cnt; --d;
        }
        int t = r / nu, part = r - t * nu;
        bj = t; bi = t + d;
        atom = (nu > 1);
        int ntk = 4 * (d + 1);
        int ntb = ntk / nu, rem = ntk % nu;
        nt = ntb + (part < rem ? 1 : 0);
        int skip = part * ntb + (part < rem ? part : rem);
        k_lo = bj * 256 + skip * BK;
    }
    int k_hi = k_lo + nt * BK;

    // half-tile ring: slot (2t+h)&3 holds half h (128 rows) of K-tile t
    __shared__ unsigned short As[4][128 * 64];   // 64 KB
    __shared__ unsigned short Bs[4][128 * 64];   // 64 KB

    int qwr = w >> 2;          // 0..1: 64-row group within 128-row quadrant half
    int qwc = w & 3;           // 0..3: 32-col group within 128-col quadrant half
    int fr = lane & 15;
    int c0 = (((lane >> 4) ^ (lane & 7)) * 8);
    int c1 = ((((lane >> 4) | 4) ^ (lane & 7)) * 8);

    // staging addressing (per 128-row half): thread t -> row tid>>3 (+64 for
    // 2nd load), chunk (tid&7)^(row&7); LDS dest linear tid*16B (+8KB)
    int srow = tid >> 3;
    int schunk = ((tid & 7) ^ (srow & 7)) * 8;
    const unsigned short* gA = Ab + (size_t)(bi * 256 + srow) * NN + schunk;
    const unsigned short* gB = Bt + (size_t)(bj * 256 + srow) * NN + schunk;

    f32x4 acc[4][4][2];        // [quad][m][n]
#pragma unroll
    for (int q = 0; q < 4; ++q)
#pragma unroll
        for (int m = 0; m < 4; ++m)
#pragma unroll
            for (int n = 0; n < 2; ++n)
                acc[q][m][n] = (f32x4){0.f, 0.f, 0.f, 0.f};

    bf16x8 a0[4], a1[4], bA0[2], bA1[2], bB0[2], bB1[2];

#define STG(XS, gX, h, slot, kk) do { \
        unsigned short* d_ = &XS[slot][0] + tid * 8; \
        GLOAD16(gX + (size_t)(h) * 128 * NN + (kk), d_); \
        GLOAD16(gX + (size_t)((h) * 128 + 64) * NN + (kk), d_ + 4096); \
    } while (0)

#define LDA(slot) do { \
        _Pragma("unroll") for (int m_ = 0; m_ < 4; ++m_) { \
            int r_ = (qwr * 64 + m_ * 16 + fr) * 64; \
            a0[m_] = *reinterpret_cast<const bf16x8*>(&As[slot][r_ + c0]); \
            a1[m_] = *reinterpret_cast<const bf16x8*>(&As[slot][r_ + c1]); \
        } \
    } while (0)

#define LDB(slot, B0V, B1V) do { \
        _Pragma("unroll") for (int n_ = 0; n_ < 2; ++n_) { \
            int r_ = (qwc * 32 + n_ * 16 + fr) * 64; \
            B0V[n_] = *reinterpret_cast<const bf16x8*>(&Bs[slot][r_ + c0]); \
            B1V[n_] = *reinterpret_cast<const bf16x8*>(&Bs[slot][r_ + c1]); \
        } \
    } while (0)

#define MFMAQ(Q, B0V, B1V) do { \
        _Pragma("unroll") for (int m_ = 0; m_ < 4; ++m_) \
        _Pragma("unroll") for (int n_ = 0; n_ < 2; ++n_) { \
            acc[Q][m_][n_] = __builtin_amdgcn_mfma_f32_16x16x32_bf16(a0[m_], B0V[n_], acc[Q][m_][n_], 0, 0, 0); \
            acc[Q][m_][n_] = __builtin_amdgcn_mfma_f32_16x16x32_bf16(a1[m_], B1V[n_], acc[Q][m_][n_], 0, 0, 0); \
        } \
    } while (0)

#define VMC4 asm volatile("s_waitcnt vmcnt(4)" ::: "memory")
#define BAR __builtin_amdgcn_s_barrier()

    // prologue: tile 0 halves, consumption order Ah0,Bh0,Bh1,Ah1 (8 loads)
    STG(As, gA, 0, 0, k_lo);
    STG(Bs, gB, 0, 0, k_lo);
    STG(Bs, gB, 1, 1, k_lo);
    STG(As, gA, 1, 1, k_lo);
    VMC4; BAR;                 // Ah0,Bh0 landed (all waves)

    for (int t = 0; t < nt; ++t) {
        int p = (t & 1) << 1;              // current slots p, p|1
        int np = p ^ 2;                    // next-tile slots
        int kkn = (t + 1 < nt) ? (k_lo + (t + 1) * BK) : k_lo;   // dummy at tail

        // P0: quad (mh0,nh0)
        LDA(p); LDB(p, bA0, bA1);
        STG(As, gA, 0, np, kkn);
        BAR;
        __builtin_amdgcn_s_setprio(1); MFMAQ(0, bA0, bA1); __builtin_amdgcn_s_setprio(0);
        VMC4; BAR;                         // Bh1(t) landed

        // P1: quad (mh0,nh1)
        LDB(p | 1, bB0, bB1);
        STG(Bs, gB, 0, np, kkn);
        BAR;
        __builtin_amdgcn_s_setprio(1); MFMAQ(1, bB0, bB1); __builtin_amdgcn_s_setprio(0);
        VMC4; BAR;                         // Ah1(t) landed

        // P2: quad (mh1,nh1)
        LDA(p | 1);
        STG(Bs, gB, 1, np | 1, kkn);
        BAR;
        __builtin_amdgcn_s_setprio(1); MFMAQ(2, bB0, bB1); __builtin_amdgcn_s_setprio(0);
        BAR;

        // P3: quad (mh1,nh0)
        STG(As, gA, 1, np | 1, kkn);
        BAR;
        __builtin_amdgcn_s_setprio(1); MFMAQ(3, bA0, bA1); __builtin_amdgcn_s_setprio(0);
        VMC4; BAR;                         // next tile's Ah0,Bh0 landed
    }
    asm volatile("s_waitcnt vmcnt(0)" ::: "memory");  // drain dummies
#undef STG
#undef LDA
#undef LDB
#undef MFMAQ
#undef VMC4
#undef BAR

    // epilogue: quad q -> (mh,nh); C/D layout col=lane&15, row=(lane>>4)*4+reg
    int r4 = (lane >> 4) * 4;
    if (atom && useW) {
        float* wb = W + (size_t)bid * 65536;
#pragma unroll
        for (int q = 0; q < 4; ++q) {
            int mh = q >> 1, nh = ((q + 1) >> 1) & 1;
#pragma unroll
            for (int m = 0; m < 4; ++m)
#pragma unroll
                for (int n = 0; n < 2; ++n) {
                    int row = mh * 128 + qwr * 64 + m * 16 + r4;
                    int col = nh * 128 + qwc * 32 + n * 16 + fr;
                    float* wp = wb + (size_t)row * 256 + col;
#pragma unroll
                    for (int r2 = 0; r2 < 4; ++r2)
                        wp[r2 * 256] = acc[q][m][n][r2];
                }
        }
    } else if (atom) {
#pragma unroll
        for (int q = 0; q < 4; ++q) {
            int mh = q >> 1, nh = ((q + 1) >> 1) & 1;
#pragma unroll
            for (int m = 0; m < 4; ++m)
#pragma unroll
                for (int n = 0; n < 2; ++n) {
                    int row = bi * 256 + mh * 128 + qwr * 64 + m * 16 + r4;
                    int col = bj * 256 + nh * 128 + qwc * 32 + n * 16 + fr;
                    float* cp = C + (size_t)row * NN + col;
#pragma unroll
                    for (int r2 = 0; r2 < 4; ++r2)
                        atomicAdd(&cp[(size_t)r2 * NN], acc[q][m][n][r2]);
                }
        }
    } else {
#pragma unroll
        for (int q = 0; q < 4; ++q) {
            int mh = q >> 1, nh = ((q + 1) >> 1) & 1;
#pragma unroll
            for (int m = 0; m < 4; ++m)
#pragma unroll
                for (int n = 0; n < 2; ++n) {
                    int row = bi * 256 + mh * 128 + qwr * 64 + m * 16 + r4;
                    int col = bj * 256 + nh * 128 + qwc * 32 + n * 16 + fr;
                    float* cp = C + (size_t)row * NN + col;
#pragma unroll
                    for (int r2 = 0; r2 < 4; ++r2)
                        cp[(size_t)r2 * NN] = acc[q][m][n][r2];
                }
        }
    }
}

// ---- merge: for each split tile, C = sum of its nu partials in W ----
__global__ __launch_bounds__(512) void merge(const float* __restrict__ W,
                                             float* __restrict__ C) {
    int z = blockIdx.x;        // 0..77
    int tid = threadIdx.x;
    int bi, bj, nu, u0; split_decode(z, bi, bj, nu, u0);
    const float4* w0 = reinterpret_cast<const float4*>(W + (size_t)u0 * 65536);
#pragma unroll 4
    for (int it = 0; it < 32; ++it) {
        int s = tid + it * 512;            // float4 index within 256x256 tile
        int row = s >> 6, c4 = s & 63;
        float4 a = w0[s];
        for (int p = 1; p < nu; ++p) {
            float4 b = w0[(size_t)p * 16384 + s];
            a.x += b.x; a.y += b.y; a.z += b.z; a.w += b.w;
        }
        float4* cp = reinterpret_cast<float4*>(C) + (size_t)(bi * 256 + row) * (NN / 4) + bj * 64 + c4;
        *cp = a;
    }
}

extern "C" void kernel_launch(void* const* d_in, const int* in_sizes, int n_in,
                              void* d_out, int out_size, void* d_ws, size_t ws_size,
                              hipStream_t stream) {
    const float* A = (const float*)d_in[0];
    const float* B = (const float*)d_in[1];
    float* C = (float*)d_out;
    unsigned short* Ab = (unsigned short*)d_ws;            // 32 MB bf16 A
    unsigned short* Bt = Ab + (size_t)NN * NN;             // 32 MB bf16 B^T
    const size_t base = (size_t)2 * NN * NN * sizeof(unsigned short);   // 64 MB
    const size_t wbytes = (size_t)NWSLOTS * 65536 * sizeof(float);      // 51.8 MB
    const int useW = (ws_size >= base + wbytes) ? 1 : 0;
    float* W = (float*)((char*)d_ws + base);

    prep<<<useW ? PGRID_W : PGRID_A, 256, 0, stream>>>(A, B, Ab, Bt, C);
    trimm<<<TGRID, 512, 0, stream>>>(Ab, Bt, C, W, useW);
    if (useW) merge<<<NSPLIT, 512, 0, stream>>>(W, C);
}

// Round 15
// 80.376 us; speedup vs baseline: 1.1456x; 1.1456x over previous
//
#include <hip/hip_runtime.h>
#include <stdint.h>

#define NN 4096
#define NB2 16         // NN / 256
#define BK 64          // K-step

// trimm grid: [0,172) units (d>=8 tiles split 2-way in K, else whole tile),
// [172,292) strict-upper 256^2 zero tiles.
#define NUNITS 172
#define ZBASE 172
#define TGRID 292

// prep grid: [0,4096) A rows, [4096,8192) B 64x64 subtiles,
// [8192,8336) zero-init for split C tiles (36 tiles x 4 stripes)
#define PGRID 8336

typedef __bf16 bf16x8 __attribute__((ext_vector_type(8)));
typedef float f32x4 __attribute__((ext_vector_type(4)));
typedef unsigned short ushort8 __attribute__((ext_vector_type(8)));

__device__ __forceinline__ unsigned short f2bf(float x) {
    union { float f; unsigned int u; } v; v.f = x;
    unsigned int u = v.u;
    u += 0x7fffu + ((u >> 16) & 1u);
    return (unsigned short)(u >> 16);
}

#define GLOAD16(g, l) __builtin_amdgcn_global_load_lds( \
    (const __attribute__((address_space(1))) unsigned int*)(g), \
    (__attribute__((address_space(3))) unsigned int*)(l), 16, 0, 0)

// split tile index z (0..35) -> (bi,bj), d descending 15..8
__device__ __forceinline__ void split_map(int z, int& bi, int& bj) {
    int d = 15;
    while (z >= NB2 - d) { z -= NB2 - d; --d; }
    bj = z; bi = z + d;
}

// ---- fused prep: A lower-prefix convert, B lower transpose-convert, split-C zero ----
__global__ __launch_bounds__(256) void prep(const float* __restrict__ A,
                                            const float* __restrict__ B,
                                            unsigned short* __restrict__ Ab,
                                            unsigned short* __restrict__ Bt,
                                            float* __restrict__ C) {
    __shared__ float tile[64][65];
    int bid = blockIdx.x;
    int tid = threadIdx.x;

    if (bid < 4096) {
        int i = bid;
        int nslots = ((i >> 8) + 1) * 32;   // fp32 prefix to 256-tile boundary
        const float4* src = reinterpret_cast<const float4*>(A + (size_t)i * NN);
        unsigned short* dst = Ab + (size_t)i * NN;
        for (int p = tid; p < nslots; p += 256) {
            float4 x0 = src[p * 2], x1 = src[p * 2 + 1];
            ushort8 o;
            o[0] = f2bf(x0.x); o[1] = f2bf(x0.y); o[2] = f2bf(x0.z); o[3] = f2bf(x0.w);
            o[4] = f2bf(x1.x); o[5] = f2bf(x1.y); o[6] = f2bf(x1.z); o[7] = f2bf(x1.w);
            *reinterpret_cast<ushort8*>(dst + p * 8) = o;
        }
        return;
    }
    if (bid < 8192) {
        int s = bid - 4096;
        int n64 = s >> 6, k64 = s & 63;
        if (k64 < (n64 & ~3)) return;       // 256-tile lower superset
        int n0 = n64 * 64, k0 = k64 * 64;
        int tx = tid & 63, ty = tid >> 6;
#pragma unroll
        for (int r = 0; r < 16; ++r) {
            int k = ty + r * 4;
            tile[k][tx] = B[(size_t)(k0 + k) * NN + n0 + tx];
        }
        __syncthreads();
#pragma unroll
        for (int r = 0; r < 16; ++r) {
            int n = ty + r * 4;
            Bt[(size_t)(n0 + n) * NN + k0 + tx] = f2bf(tile[tx][n]);
        }
        return;
    }
    // zero-init split C tile (atomicAdd targets; re-zeroed every call)
    {
        int zb = bid - 8192;            // 0..143
        int bi, bj; split_map(zb >> 2, bi, bj);
        int part = zb & 3;              // 64-row stripe
        float4 zf = make_float4(0.f, 0.f, 0.f, 0.f);
        float4* cp = reinterpret_cast<float4*>(C + (size_t)(bi * 256 + part * 64) * NN + (size_t)bj * 256);
#pragma unroll
        for (int i2 = 0; i2 < 16; ++i2) {
            int slot = tid + i2 * 256;
            int row = slot >> 6, c4 = slot & 63;
            cp[(size_t)row * (NN / 4) + c4] = zf;
        }
    }
}

// ---- triangular GEMM: 256^2, 8 waves, 4-phase/K-tile, half-tile ring,
//      counted vmcnt(4) (R14 engine); 2-way split-K on d>=8, atomic merge ----
__global__ __launch_bounds__(512, 1) void trimm(const unsigned short* __restrict__ Ab,
                                                const unsigned short* __restrict__ Bt,
                                                float* __restrict__ C) {
    int bid = blockIdx.x;
    int tid = threadIdx.x;
    int lane = tid & 63;
    int w = tid >> 6;

    if (bid >= ZBASE) {
        // strict upper 256^2 tile: zero-fill
        int r = bid - ZBASE, bi = 0;
        while (r >= NB2 - 1 - bi) { r -= NB2 - 1 - bi; ++bi; }
        int bj = bi + 1 + r;
        float4 z = make_float4(0.f, 0.f, 0.f, 0.f);
        float4* cp = reinterpret_cast<float4*>(C + (size_t)bi * 256 * NN + (size_t)bj * 256);
#pragma unroll
        for (int i2 = 0; i2 < 32; ++i2) {
            int slot = tid + i2 * 512;
            int row = slot >> 6, c4 = slot & 63;
            cp[(size_t)row * (NN / 4) + c4] = z;
        }
        return;
    }

    // unit decode (R7-validated): d desc 15..0; d>=8 -> 2 K-units, else 1.
    int bi, bj, k_lo, nt;
    bool atom;
    {
        int r = bid, d = 15, nu;
        for (;;) {
            nu = (d >= 8) ? 2 : 1;
            int cnt = (NB2 - d) * nu;
            if (r < cnt) break;
            r -= cnt; --d;
        }
        int t = r / nu, part = r - t * nu;
        bj = t; bi = t + d;
        atom = (nu == 2);
        int ntk = 4 * (d + 1);         // total K-tiles (BK=64) for this tile
        nt = ntk / nu;                 // K-tiles in this unit
        k_lo = bj * 256 + part * nt * BK;
    }
    int k_hi = k_lo + nt * BK;
    (void)k_hi;

    // half-tile ring: slot (2t+h)&3 holds half h (128 rows) of K-tile t
    __shared__ unsigned short As[4][128 * 64];   // 64 KB
    __shared__ unsigned short Bs[4][128 * 64];   // 64 KB

    int qwr = w >> 2;          // 0..1: 64-row group within 128-row half
    int qwc = w & 3;           // 0..3: 32-col group within 128-col half
    int fr = lane & 15;
    int c0 = (((lane >> 4) ^ (lane & 7)) * 8);
    int c1 = ((((lane >> 4) | 4) ^ (lane & 7)) * 8);

    // staging: thread t -> row tid>>3 (+64 for 2nd load), chunk (tid&7)^(row&7)
    int srow = tid >> 3;
    int schunk = ((tid & 7) ^ (srow & 7)) * 8;
    const unsigned short* gA = Ab + (size_t)(bi * 256 + srow) * NN + schunk;
    const unsigned short* gB = Bt + (size_t)(bj * 256 + srow) * NN + schunk;

    f32x4 acc[4][4][2];        // [quad][m][n]
#pragma unroll
    for (int q = 0; q < 4; ++q)
#pragma unroll
        for (int m = 0; m < 4; ++m)
#pragma unroll
            for (int n = 0; n < 2; ++n)
                acc[q][m][n] = (f32x4){0.f, 0.f, 0.f, 0.f};

    bf16x8 a0[4], a1[4], bA0[2], bA1[2], bB0[2], bB1[2];

#define STG(XS, gX, h, slot, kk) do { \
        unsigned short* d_ = &XS[slot][0] + tid * 8; \
        GLOAD16(gX + (size_t)(h) * 128 * NN + (kk), d_); \
        GLOAD16(gX + (size_t)((h) * 128 + 64) * NN + (kk), d_ + 4096); \
    } while (0)

#define LDA(slot) do { \
        _Pragma("unroll") for (int m_ = 0; m_ < 4; ++m_) { \
            int r_ = (qwr * 64 + m_ * 16 + fr) * 64; \
            a0[m_] = *reinterpret_cast<const bf16x8*>(&As[slot][r_ + c0]); \
            a1[m_] = *reinterpret_cast<const bf16x8*>(&As[slot][r_ + c1]); \
        } \
    } while (0)

#define LDB(slot, B0V, B1V) do { \
        _Pragma("unroll") for (int n_ = 0; n_ < 2; ++n_) { \
            int r_ = (qwc * 32 + n_ * 16 + fr) * 64; \
            B0V[n_] = *reinterpret_cast<const bf16x8*>(&Bs[slot][r_ + c0]); \
            B1V[n_] = *reinterpret_cast<const bf16x8*>(&Bs[slot][r_ + c1]); \
        } \
    } while (0)

#define MFMAQ(Q, B0V, B1V) do { \
        _Pragma("unroll") for (int m_ = 0; m_ < 4; ++m_) \
        _Pragma("unroll") for (int n_ = 0; n_ < 2; ++n_) { \
            acc[Q][m_][n_] = __builtin_amdgcn_mfma_f32_16x16x32_bf16(a0[m_], B0V[n_], acc[Q][m_][n_], 0, 0, 0); \
            acc[Q][m_][n_] = __builtin_amdgcn_mfma_f32_16x16x32_bf16(a1[m_], B1V[n_], acc[Q][m_][n_], 0, 0, 0); \
        } \
    } while (0)

#define VMC4 asm volatile("s_waitcnt vmcnt(4)" ::: "memory")
#define BAR __builtin_amdgcn_s_barrier()

    // prologue: tile 0 halves, consumption order Ah0,Bh0,Bh1,Ah1 (8 loads)
    STG(As, gA, 0, 0, k_lo);
    STG(Bs, gB, 0, 0, k_lo);
    STG(Bs, gB, 1, 1, k_lo);
    STG(As, gA, 1, 1, k_lo);
    VMC4; BAR;                 // Ah0,Bh0 landed (all waves)

    for (int t = 0; t < nt; ++t) {
        int p = (t & 1) << 1;              // current slots p, p|1
        int np = p ^ 2;                    // next-tile slots
        int kkn = (t + 1 < nt) ? (k_lo + (t + 1) * BK) : k_lo;   // dummy at tail

        // P0: quad (mh0,nh0)
        LDA(p); LDB(p, bA0, bA1);
        STG(As, gA, 0, np, kkn);
        BAR;
        __builtin_amdgcn_s_setprio(1); MFMAQ(0, bA0, bA1); __builtin_amdgcn_s_setprio(0);
        VMC4; BAR;                         // Bh1(t) landed

        // P1: quad (mh0,nh1)
        LDB(p | 1, bB0, bB1);
        STG(Bs, gB, 0, np, kkn);
        BAR;
        __builtin_amdgcn_s_setprio(1); MFMAQ(1, bB0, bB1); __builtin_amdgcn_s_setprio(0);
        VMC4; BAR;                         // Ah1(t) landed

        // P2: quad (mh1,nh1)
        LDA(p | 1);
        STG(Bs, gB, 1, np | 1, kkn);
        BAR;
        __builtin_amdgcn_s_setprio(1); MFMAQ(2, bB0, bB1); __builtin_amdgcn_s_setprio(0);
        BAR;

        // P3: quad (mh1,nh0)
        STG(As, gA, 1, np | 1, kkn);
        BAR;
        __builtin_amdgcn_s_setprio(1); MFMAQ(3, bA0, bA1); __builtin_amdgcn_s_setprio(0);
        VMC4; BAR;                         // next tile's Ah0,Bh0 landed
    }
    asm volatile("s_waitcnt vmcnt(0)" ::: "memory");  // drain dummies
#undef STG
#undef LDA
#undef LDB
#undef MFMAQ
#undef VMC4
#undef BAR

    // epilogue: quad q -> (mh,nh); C/D layout col=lane&15, row=(lane>>4)*4+reg
    int r4 = (lane >> 4) * 4;
    if (atom) {
#pragma unroll
        for (int q = 0; q < 4; ++q) {
            int mh = q >> 1, nh = ((q + 1) >> 1) & 1;
#pragma unroll
            for (int m = 0; m < 4; ++m)
#pragma unroll
                for (int n = 0; n < 2; ++n) {
                    int row = bi * 256 + mh * 128 + qwr * 64 + m * 16 + r4;
                    int col = bj * 256 + nh * 128 + qwc * 32 + n * 16 + fr;
                    float* cp = C + (size_t)row * NN + col;
#pragma unroll
                    for (int r2 = 0; r2 < 4; ++r2)
                        atomicAdd(&cp[(size_t)r2 * NN], acc[q][m][n][r2]);
                }
        }
    } else {
#pragma unroll
        for (int q = 0; q < 4; ++q) {
            int mh = q >> 1, nh = ((q + 1) >> 1) & 1;
#pragma unroll
            for (int m = 0; m < 4; ++m)
#pragma unroll
                for (int n = 0; n < 2; ++n) {
                    int row = bi * 256 + mh * 128 + qwr * 64 + m * 16 + r4;
                    int col = bj * 256 + nh * 128 + qwc * 32 + n * 16 + fr;
                    float* cp = C + (size_t)row * NN + col;
#pragma unroll
                    for (int r2 = 0; r2 < 4; ++r2)
                        cp[(size_t)r2 * NN] = acc[q][m][n][r2];
                }
        }
    }
}

extern "C" void kernel_launch(void* const* d_in, const int* in_sizes, int n_in,
                              void* d_out, int out_size, void* d_ws, size_t ws_size,
                              hipStream_t stream) {
    const float* A = (const float*)d_in[0];
    const float* B = (const float*)d_in[1];
    float* C = (float*)d_out;
    unsigned short* Ab = (unsigned short*)d_ws;            // 32 MB bf16 A
    unsigned short* Bt = Ab + (size_t)NN * NN;             // 32 MB bf16 B^T
    prep<<<PGRID, 256, 0, stream>>>(A, B, Ab, Bt, C);
    trimm<<<TGRID, 512, 0, stream>>>(Ab, Bt, C);
}

// Round 16
// 76.749 us; speedup vs baseline: 1.1997x; 1.0472x over previous
//
#include <hip/hip_runtime.h>
#include <stdint.h>

#define NN 4096
#define NB2 16         // NN / 256
#define BK 64          // K-step

// trimm grid: [0,260) units (d desc; nu(d)=ceil((d+1)/4) K-units/tile, each
// <=16 K-tiles), [260,380) strict-upper 256^2 zero tiles.
#define NUNITS 260
#define ZBASE 260
#define TGRID 380
#define NSPLIT 78      // tiles with nu>=2 (d>=4)
#define NWSLOTS 202    // units belonging to split tiles (bids 0..201)

// prep grid: [0,4096) A rows, [4096,8192) B 64x64 subtiles;
// fallback adds [8192,8504) zero-init (78 tiles x 4 stripes)
#define PGRID_W 8192
#define PGRID_A 8504

typedef __bf16 bf16x8 __attribute__((ext_vector_type(8)));
typedef float f32x4 __attribute__((ext_vector_type(4)));
typedef unsigned short ushort8 __attribute__((ext_vector_type(8)));

__device__ __forceinline__ unsigned short f2bf(float x) {
    union { float f; unsigned int u; } v; v.f = x;
    unsigned int u = v.u;
    u += 0x7fffu + ((u >> 16) & 1u);
    return (unsigned short)(u >> 16);
}

#define GLOAD16(g, l) __builtin_amdgcn_global_load_lds( \
    (const __attribute__((address_space(1))) unsigned int*)(g), \
    (__attribute__((address_space(3))) unsigned int*)(l), 16, 0, 0)

// split tile index z (0..77) -> (bi,bj,nu,u0); d descending 15..4
__device__ __forceinline__ void split_decode(int z, int& bi, int& bj, int& nu, int& u0) {
    int d = 15, acc = 0;
    for (;;) {
        nu = (d + 4) >> 2;
        int cnt = NB2 - d;
        if (z < cnt) { bj = z; bi = z + d; u0 = acc + z * nu; return; }
        z -= cnt; acc += cnt * nu; --d;
    }
}

// ---- fused prep ----
__global__ __launch_bounds__(256) void prep(const float* __restrict__ A,
                                            const float* __restrict__ B,
                                            unsigned short* __restrict__ Ab,
                                            unsigned short* __restrict__ Bt,
                                            float* __restrict__ C) {
    __shared__ float tile[64][65];
    int bid = blockIdx.x;
    int tid = threadIdx.x;

    if (bid < 4096) {
        int i = bid;
        int nslots = ((i >> 8) + 1) * 32;
        const float4* src = reinterpret_cast<const float4*>(A + (size_t)i * NN);
        unsigned short* dst = Ab + (size_t)i * NN;
        for (int p = tid; p < nslots; p += 256) {
            float4 x0 = src[p * 2], x1 = src[p * 2 + 1];
            ushort8 o;
            o[0] = f2bf(x0.x); o[1] = f2bf(x0.y); o[2] = f2bf(x0.z); o[3] = f2bf(x0.w);
            o[4] = f2bf(x1.x); o[5] = f2bf(x1.y); o[6] = f2bf(x1.z); o[7] = f2bf(x1.w);
            *reinterpret_cast<ushort8*>(dst + p * 8) = o;
        }
        return;
    }
    if (bid < 8192) {
        int s = bid - 4096;
        int n64 = s >> 6, k64 = s & 63;
        if (k64 < (n64 & ~3)) return;
        int n0 = n64 * 64, k0 = k64 * 64;
        int tx = tid & 63, ty = tid >> 6;
#pragma unroll
        for (int r = 0; r < 16; ++r) {
            int k = ty + r * 4;
            tile[k][tx] = B[(size_t)(k0 + k) * NN + n0 + tx];
        }
        __syncthreads();
#pragma unroll
        for (int r = 0; r < 16; ++r) {
            int n = ty + r * 4;
            Bt[(size_t)(n0 + n) * NN + k0 + tx] = f2bf(tile[tx][n]);
        }
        return;
    }
    // atomic-fallback zero-init for split C tiles
    {
        int z = bid - 8192;
        int bi, bj, nu, u0; split_decode(z >> 2, bi, bj, nu, u0);
        int part = z & 3;
        float4 zf = make_float4(0.f, 0.f, 0.f, 0.f);
        float4* cp = reinterpret_cast<float4*>(C + (size_t)(bi * 256 + part * 64) * NN + (size_t)bj * 256);
#pragma unroll
        for (int i2 = 0; i2 < 16; ++i2) {
            int slot = tid + i2 * 256;
            int row = slot >> 6, c4 = slot & 63;
            cp[(size_t)row * (NN / 4) + c4] = zf;
        }
    }
}

// ---- triangular GEMM: 256^2, 8 waves, 2 fused phases/K-tile, half-tile ring,
//      counted vmcnt(2)/vmcnt(4) ----
__global__ __launch_bounds__(512, 1) void trimm(const unsigned short* __restrict__ Ab,
                                                const unsigned short* __restrict__ Bt,
                                                float* __restrict__ C,
                                                float* __restrict__ W,
                                                int useW) {
    int bid = blockIdx.x;
    int tid = threadIdx.x;
    int lane = tid & 63;
    int w = tid >> 6;

    if (bid >= ZBASE) {
        // strict upper 256^2 tile: zero-fill
        int r = bid - ZBASE, bi = 0;
        while (r >= NB2 - 1 - bi) { r -= NB2 - 1 - bi; ++bi; }
        int bj = bi + 1 + r;
        float4 z = make_float4(0.f, 0.f, 0.f, 0.f);
        float4* cp = reinterpret_cast<float4*>(C + (size_t)bi * 256 * NN + (size_t)bj * 256);
#pragma unroll
        for (int i2 = 0; i2 < 32; ++i2) {
            int slot = tid + i2 * 512;
            int row = slot >> 6, c4 = slot & 63;
            cp[(size_t)row * (NN / 4) + c4] = z;
        }
        return;
    }

    // unit decode: d desc 15..0; nu=ceil((d+1)/4); ntk=4(d+1)
    int bi, bj, k_lo, nt;
    bool atom;
    {
        int r = bid, d = 15, nu;
        for (;;) {
            nu = (d + 4) >> 2;
            int cnt = (NB2 - d) * nu;
            if (r < cnt) break;
            r -= cnt; --d;
        }
        int t = r / nu, part = r - t * nu;
        bj = t; bi = t + d;
        atom = (nu > 1);
        int ntk = 4 * (d + 1);
        int ntb = ntk / nu, rem = ntk % nu;
        nt = ntb + (part < rem ? 1 : 0);
        int skip = part * ntb + (part < rem ? part : rem);
        k_lo = bj * 256 + skip * BK;
    }

    // half-tile ring: slot (2t+h)&3 holds half h (128 rows) of K-tile t
    __shared__ unsigned short As[4][128 * 64];   // 64 KB
    __shared__ unsigned short Bs[4][128 * 64];   // 64 KB

    int qwr = w >> 2;          // 0..1: 64-row group within 128-row half
    int qwc = w & 3;           // 0..3: 32-col group within 128-col half
    int fr = lane & 15;
    int c0 = (((lane >> 4) ^ (lane & 7)) * 8);
    int c1 = ((((lane >> 4) | 4) ^ (lane & 7)) * 8);

    int srow = tid >> 3;
    int schunk = ((tid & 7) ^ (srow & 7)) * 8;
    const unsigned short* gA = Ab + (size_t)(bi * 256 + srow) * NN + schunk;
    const unsigned short* gB = Bt + (size_t)(bj * 256 + srow) * NN + schunk;

    f32x4 acc[4][4][2];        // [quad][m][n]
#pragma unroll
    for (int q = 0; q < 4; ++q)
#pragma unroll
        for (int m = 0; m < 4; ++m)
#pragma unroll
            for (int n = 0; n < 2; ++n)
                acc[q][m][n] = (f32x4){0.f, 0.f, 0.f, 0.f};

    bf16x8 a0[4], a1[4], bh0c0[2], bh0c1[2], bh1c0[2], bh1c1[2];

#define STG(XS, gX, h, slot, kk) do { \
        unsigned short* d_ = &XS[slot][0] + tid * 8; \
        GLOAD16(gX + (size_t)(h) * 128 * NN + (kk), d_); \
        GLOAD16(gX + (size_t)((h) * 128 + 64) * NN + (kk), d_ + 4096); \
    } while (0)

#define LDAH(slot, AV0, AV1) do { \
        _Pragma("unroll") for (int m_ = 0; m_ < 4; ++m_) { \
            int r_ = (qwr * 64 + m_ * 16 + fr) * 64; \
            AV0[m_] = *reinterpret_cast<const bf16x8*>(&As[slot][r_ + c0]); \
            AV1[m_] = *reinterpret_cast<const bf16x8*>(&As[slot][r_ + c1]); \
        } \
    } while (0)

#define LDBH(slot, B0V, B1V) do { \
        _Pragma("unroll") for (int n_ = 0; n_ < 2; ++n_) { \
            int r_ = (qwc * 32 + n_ * 16 + fr) * 64; \
            B0V[n_] = *reinterpret_cast<const bf16x8*>(&Bs[slot][r_ + c0]); \
            B1V[n_] = *reinterpret_cast<const bf16x8*>(&Bs[slot][r_ + c1]); \
        } \
    } while (0)

#define MFMAQ(Q, AV0, AV1, B0V, B1V) do { \
        _Pragma("unroll") for (int m_ = 0; m_ < 4; ++m_) \
        _Pragma("unroll") for (int n_ = 0; n_ < 2; ++n_) { \
            acc[Q][m_][n_] = __builtin_amdgcn_mfma_f32_16x16x32_bf16(AV0[m_], B0V[n_], acc[Q][m_][n_], 0, 0, 0); \
            acc[Q][m_][n_] = __builtin_amdgcn_mfma_f32_16x16x32_bf16(AV1[m_], B1V[n_], acc[Q][m_][n_], 0, 0, 0); \
        } \
    } while (0)

#define BAR __builtin_amdgcn_s_barrier()

    // prologue: tile 0 halves, issue order Ah0,Bh0,Bh1,Ah1 (8 loads)
    STG(As, gA, 0, 0, k_lo);
    STG(Bs, gB, 0, 0, k_lo);
    STG(Bs, gB, 1, 1, k_lo);
    STG(As, gA, 1, 1, k_lo);

    for (int t = 0; t < nt; ++t) {
        int p = (t & 1) << 1;              // current slots p, p|1
        int np = p ^ 2;                    // next-tile slots
        int kkn = (t + 1 < nt) ? (k_lo + (t + 1) * BK) : k_lo;   // dummy at tail

        // PhA: quads (mh0,nh0) + (mh0,nh1); needs Ah0,Bh0,Bh1 of tile t
        asm volatile("s_waitcnt vmcnt(2)" ::: "memory");
        BAR;
        LDAH(p, a0, a1);                   // Ah0
        LDBH(p, bh0c0, bh0c1);             // Bh0
        LDBH(p | 1, bh1c0, bh1c1);         // Bh1
        __builtin_amdgcn_s_setprio(1);
        MFMAQ(0, a0, a1, bh0c0, bh0c1);
        MFMAQ(1, a0, a1, bh1c0, bh1c1);
        __builtin_amdgcn_s_setprio(0);
        STG(As, gA, 0, np, kkn);           // t+1: Ah0
        STG(Bs, gB, 0, np, kkn);           // t+1: Bh0

        // PhB: quads (mh1,nh1) + (mh1,nh0); needs Ah1 of tile t
        asm volatile("s_waitcnt vmcnt(4)" ::: "memory");
        BAR;
        LDAH(p | 1, a0, a1);               // Ah1 (reuse a regs)
        __builtin_amdgcn_s_setprio(1);
        MFMAQ(2, a0, a1, bh1c0, bh1c1);
        MFMAQ(3, a0, a1, bh0c0, bh0c1);
        __builtin_amdgcn_s_setprio(0);
        STG(Bs, gB, 1, np | 1, kkn);       // t+1: Bh1
        STG(As, gA, 1, np | 1, kkn);       // t+1: Ah1
    }
    asm volatile("s_waitcnt vmcnt(0)" ::: "memory");  // drain dummies
#undef STG
#undef LDAH
#undef LDBH
#undef MFMAQ
#undef BAR

    // epilogue: quad q -> (mh,nh); C/D layout col=lane&15, row=(lane>>4)*4+reg
    int r4 = (lane >> 4) * 4;
    if (atom && useW) {
        float* wb = W + (size_t)bid * 65536;
#pragma unroll
        for (int q = 0; q < 4; ++q) {
            int mh = q >> 1, nh = ((q + 1) >> 1) & 1;
#pragma unroll
            for (int m = 0; m < 4; ++m)
#pragma unroll
                for (int n = 0; n < 2; ++n) {
                    int row = mh * 128 + qwr * 64 + m * 16 + r4;
                    int col = nh * 128 + qwc * 32 + n * 16 + fr;
                    float* wp = wb + (size_t)row * 256 + col;
#pragma unroll
                    for (int r2 = 0; r2 < 4; ++r2)
                        wp[r2 * 256] = acc[q][m][n][r2];
                }
        }
    } else if (atom) {
#pragma unroll
        for (int q = 0; q < 4; ++q) {
            int mh = q >> 1, nh = ((q + 1) >> 1) & 1;
#pragma unroll
            for (int m = 0; m < 4; ++m)
#pragma unroll
                for (int n = 0; n < 2; ++n) {
                    int row = bi * 256 + mh * 128 + qwr * 64 + m * 16 + r4;
                    int col = bj * 256 + nh * 128 + qwc * 32 + n * 16 + fr;
                    float* cp = C + (size_t)row * NN + col;
#pragma unroll
                    for (int r2 = 0; r2 < 4; ++r2)
                        atomicAdd(&cp[(size_t)r2 * NN], acc[q][m][n][r2]);
                }
        }
    } else {
#pragma unroll
        for (int q = 0; q < 4; ++q) {
            int mh = q >> 1, nh = ((q + 1) >> 1) & 1;
#pragma unroll
            for (int m = 0; m < 4; ++m)
#pragma unroll
                for (int n = 0; n < 2; ++n) {
                    int row = bi * 256 + mh * 128 + qwr * 64 + m * 16 + r4;
                    int col = bj * 256 + nh * 128 + qwc * 32 + n * 16 + fr;
                    float* cp = C + (size_t)row * NN + col;
#pragma unroll
                    for (int r2 = 0; r2 < 4; ++r2)
                        cp[(size_t)r2 * NN] = acc[q][m][n][r2];
                }
        }
    }
}

// ---- merge: 8 blocks per split tile (32-row stripes), C = sum of partials ----
__global__ __launch_bounds__(256) void merge(const float* __restrict__ W,
                                             float* __restrict__ C) {
    int blk = blockIdx.x;      // 0..623
    int z = blk >> 3;
    int sub = blk & 7;
    int tid = threadIdx.x;
    int bi, bj, nu, u0; split_decode(z, bi, bj, nu, u0);
    const float4* w0 = reinterpret_cast<const float4*>(W + (size_t)u0 * 65536) + sub * 2048;
#pragma unroll 2
    for (int it = 0; it < 8; ++it) {
        int s = tid + it * 256;            // 0..2047 within stripe
        int row = s >> 6, c4 = s & 63;
        float4 a = w0[s];
        for (int p = 1; p < nu; ++p) {
            float4 b = w0[(size_t)p * 16384 + s];
            a.x += b.x; a.y += b.y; a.z += b.z; a.w += b.w;
        }
        float4* cp = reinterpret_cast<float4*>(C) +
                     (size_t)(bi * 256 + sub * 32 + row) * (NN / 4) + bj * 64 + c4;
        *cp = a;
    }
}

extern "C" void kernel_launch(void* const* d_in, const int* in_sizes, int n_in,
                              void* d_out, int out_size, void* d_ws, size_t ws_size,
                              hipStream_t stream) {
    const float* A = (const float*)d_in[0];
    const float* B = (const float*)d_in[1];
    float* C = (float*)d_out;
    unsigned short* Ab = (unsigned short*)d_ws;            // 32 MB bf16 A
    unsigned short* Bt = Ab + (size_t)NN * NN;             // 32 MB bf16 B^T
    const size_t base = (size_t)2 * NN * NN * sizeof(unsigned short);   // 64 MB
    const size_t wbytes = (size_t)NWSLOTS * 65536 * sizeof(float);      // 51.8 MB
    const int useW = (ws_size >= base + wbytes) ? 1 : 0;
    float* W = (float*)((char*)d_ws + base);

    prep<<<useW ? PGRID_W : PGRID_A, 256, 0, stream>>>(A, B, Ab, Bt, C);
    trimm<<<TGRID, 512, 0, stream>>>(Ab, Bt, C, W, useW);
    if (useW) merge<<<NSPLIT * 8, 256, 0, stream>>>(W, C);
}